// Round 2
// 1007.932 us; speedup vs baseline: 1.0115x; 1.0115x over previous
//
#include <hip/hip_runtime.h>
#include <math.h>

typedef unsigned short u16;
typedef unsigned int   u32;
typedef __attribute__((ext_vector_type(8))) short short8;
typedef __attribute__((ext_vector_type(4))) float floatx4;
typedef __attribute__((ext_vector_type(4))) u16   u16x4;

#define NE   16      // experts
#define CAP  2048    // capacity per expert
#define HD   2048    // hidden
#define FD   1024    // intermediate
#define NT   4096    // tokens

// ---------- helpers ----------
__device__ __forceinline__ u16 f2bf(float f) {
    u32 u = __builtin_bit_cast(u32, f);
    u = (u + 0x7FFFu + ((u >> 16) & 1u)) >> 16;   // RNE
    return (u16)u;
}

typedef const u32 __attribute__((address_space(1))) glb_u32;
typedef u32 __attribute__((address_space(3)))       lds_u32;

__device__ __forceinline__ void cp16(const void* g, void* l) {
    __builtin_amdgcn_global_load_lds((glb_u32*)g, (lds_u32*)l, 16, 0, 0);
}

__device__ __forceinline__ floatx4 mfma_bf16(short8 a, short8 b, floatx4 c) {
    return __builtin_amdgcn_mfma_f32_16x16x32_bf16(a, b, c, 0, 0, 0);
}

// ---------- x -> bf16 ----------
__global__ void cvt_x_kernel(const float* __restrict__ x, u16* __restrict__ xb) {
    int i = blockIdx.x * 256 + threadIdx.x;
    float4 v = reinterpret_cast<const float4*>(x)[i];
    u16x4 o; o.x = f2bf(v.x); o.y = f2bf(v.y); o.z = f2bf(v.z); o.w = f2bf(v.w);
    reinterpret_cast<u16x4*>(xb)[i] = o;
}

// ---------- transpose + convert: in [R][Cc] fp32 -> out [Cc][R] bf16 (per expert) ----------
__global__ void transpose_cvt(const float* __restrict__ in, u16* __restrict__ out,
                              int R, int Cc) {
    __shared__ u16 tile[64][65];
    int e = blockIdx.y;
    int tilesC = Cc >> 6;
    int tr = blockIdx.x / tilesC;
    int tc = blockIdx.x - tr * tilesC;
    const float* ip = in + (size_t)e * R * Cc + (size_t)(tr * 64) * Cc + tc * 64;
    u16* op = out + (size_t)e * R * Cc + (size_t)(tc * 64) * R + tr * 64;
    int c  = threadIdx.x & 63;
    int r0 = threadIdx.x >> 6;
    #pragma unroll
    for (int i = 0; i < 16; ++i) {
        int r = r0 + (i << 2);
        tile[r][c] = f2bf(ip[(size_t)r * Cc + c]);
    }
    __syncthreads();
    int rr = threadIdx.x & 63;
    int c0 = threadIdx.x >> 6;
    #pragma unroll
    for (int i = 0; i < 16; ++i) {
        int cc = c0 + (i << 2);
        op[(size_t)cc * R + rr] = tile[rr][cc];
    }
}

// ---------- router: fp64-exact logits, top-4, softmax, dispatch ----------
__global__ void router_kernel(const float* __restrict__ x, const float* __restrict__ gw,
                              float* __restrict__ logits, int* __restrict__ tok,
                              float* __restrict__ wts, int* __restrict__ cnt) {
    int t = blockIdx.x;
    int l = threadIdx.x;      // 0..63
    const float* xr = x + (size_t)t * HD;
    double acc[NE];
    #pragma unroll
    for (int e = 0; e < NE; ++e) acc[e] = 0.0;
    for (int i = 0; i < HD / 64; ++i) {
        float xv = xr[l + (i << 6)];
        const float* g = gw + (size_t)(l + (i << 6)) * NE;
        #pragma unroll
        for (int e = 0; e < NE; ++e) acc[e] += (double)xv * (double)g[e];
    }
    #pragma unroll
    for (int e = 0; e < NE; ++e) {
        double v = acc[e];
        #pragma unroll
        for (int off = 1; off < 64; off <<= 1) v += __shfl_xor(v, off, 64);
        acc[e] = v;
    }
    if (l == 0) {
        #pragma unroll
        for (int e = 0; e < NE; ++e) logits[(size_t)t * NE + e] = (float)acc[e];
        int bi[4]; double bv[4];
        u32 used = 0;
        for (int k = 0; k < 4; ++k) {
            int best = 0; double bvv = -1e300;
            for (int e = 0; e < NE; ++e)
                if (!((used >> e) & 1u) && acc[e] > bvv) { bvv = acc[e]; best = e; }
            bi[k] = best; bv[k] = bvv; used |= 1u << best;
        }
        double s = 0.0, wv[4];
        for (int k = 0; k < 4; ++k) { wv[k] = exp(bv[k] - bv[0]); s += wv[k]; }
        for (int k = 0; k < 4; ++k) {
            int e = bi[k];
            int pos = atomicAdd(&cnt[e], 1);
            if (pos < CAP) {
                tok[e * CAP + pos] = t;
                wts[e * CAP + pos] = (float)(wv[k] / s);
            }
        }
    }
}

// ---------- GEMM1: fused gate+up, 128x(64+64) tile, BK=64, double-buffered prefetch ----------
// LDS XOR-swizzled as before (swizzle on GLOBAL source address; global_load_lds dest is
// pinned to lane*16). T3-minimal schedule: stage tile t+1 BEFORE computing tile t, single
// barrier per K-step (the compiler's barrier drain covers vmcnt for the staged loads).
__global__ __launch_bounds__(256) void gemm_gateup(
        const u16* __restrict__ xb, const u16* __restrict__ wgT, const u16* __restrict__ wuT,
        const int* __restrict__ tok, const int* __restrict__ cnt, u16* __restrict__ hbuf) {
    int bid = blockIdx.x;
    int e  = bid >> 8;
    int mt = (bid >> 4) & 15;
    int nt = bid & 15;
    int ne = cnt[e]; if (ne > CAP) ne = CAP;
    int row0 = mt << 7;
    if (row0 >= ne) return;

    __shared__ u16 As[2][128 * 64];
    __shared__ u16 Bg[2][64 * 64];
    __shared__ u16 Bu[2][64 * 64];
    __shared__ int toklds[128];

    int tid = threadIdx.x;
    if (tid < 128) {
        int r = row0 + tid;
        toklds[tid] = tok[e * CAP + (r < ne ? r : 0)];
    }
    __syncthreads();

    const u16* asrc[4];
    #pragma unroll
    for (int p = 0; p < 4; ++p) {
        int idx = tid + (p << 8);
        int r = idx >> 3;
        int c = (idx & 7) ^ (r & 7);            // XOR swizzle
        asrc[p] = xb + (size_t)toklds[r] * HD + (c << 3);
    }
    const u16* bgb = wgT + ((size_t)e * FD + (nt << 6)) * HD;
    const u16* bub = wuT + ((size_t)e * FD + (nt << 6)) * HD;
    const u16* bgsrc[2]; const u16* busrc[2];
    #pragma unroll
    for (int p = 0; p < 2; ++p) {
        int idx = tid + (p << 8);
        int r = idx >> 3;
        int c = (idx & 7) ^ (r & 7);            // XOR swizzle
        bgsrc[p] = bgb + (size_t)r * HD + (c << 3);
        busrc[p] = bub + (size_t)r * HD + (c << 3);
    }

    floatx4 accg[4][2], accu[4][2];
    #pragma unroll
    for (int i = 0; i < 4; ++i)
        #pragma unroll
        for (int j = 0; j < 2; ++j) {
            accg[i][j] = floatx4{0.f, 0.f, 0.f, 0.f};
            accu[i][j] = floatx4{0.f, 0.f, 0.f, 0.f};
        }

    int l = tid & 63, w = tid >> 6;
    int wm = (w >> 1) << 6;   // 0 / 64
    int wn = (w & 1) << 5;    // 0 / 32
    int lr = l & 15, q = l >> 4;
    int sw = lr & 7;          // swizzle key for fragment reads

    // prologue: stage tile 0 into buffer 0
    #pragma unroll
    for (int p = 0; p < 4; ++p) cp16(asrc[p], &As[0][(tid + (p << 8)) << 3]);
    #pragma unroll
    for (int p = 0; p < 2; ++p) {
        cp16(bgsrc[p], &Bg[0][(tid + (p << 8)) << 3]);
        cp16(busrc[p], &Bu[0][(tid + (p << 8)) << 3]);
    }
    __syncthreads();                            // drains vmcnt -> tile 0 visible

    int cur = 0;
    for (int k0 = 64; k0 <= HD; k0 += 64) {
        // issue next-tile loads first (overlap HBM/L2 latency with compute below)
        if (k0 < HD) {
            int nx = cur ^ 1;
            #pragma unroll
            for (int p = 0; p < 4; ++p) cp16(asrc[p] + k0, &As[nx][(tid + (p << 8)) << 3]);
            #pragma unroll
            for (int p = 0; p < 2; ++p) {
                cp16(bgsrc[p] + k0, &Bg[nx][(tid + (p << 8)) << 3]);
                cp16(busrc[p] + k0, &Bu[nx][(tid + (p << 8)) << 3]);
            }
        }
        // compute tile (k0-64) from buffer cur
        #pragma unroll
        for (int kk = 0; kk < 2; ++kk) {
            int ch = ((kk << 2) + q) ^ sw;      // swizzled chunk
            short8 af[4], bg[2], bu[2];
            #pragma unroll
            for (int mi = 0; mi < 4; ++mi)
                af[mi] = *(const short8*)&As[cur][((wm + mi * 16 + lr) << 6) + (ch << 3)];
            #pragma unroll
            for (int ni = 0; ni < 2; ++ni) {
                bg[ni] = *(const short8*)&Bg[cur][((wn + ni * 16 + lr) << 6) + (ch << 3)];
                bu[ni] = *(const short8*)&Bu[cur][((wn + ni * 16 + lr) << 6) + (ch << 3)];
            }
            #pragma unroll
            for (int mi = 0; mi < 4; ++mi)
                #pragma unroll
                for (int ni = 0; ni < 2; ++ni) {
                    accg[mi][ni] = mfma_bf16(af[mi], bg[ni], accg[mi][ni]);
                    accu[mi][ni] = mfma_bf16(af[mi], bu[ni], accu[mi][ni]);
                }
        }
        __syncthreads();  // single barrier: staged tile complete + everyone done with cur
        cur ^= 1;
    }

    // epilogue: h = silu(g)*u, bf16 store
    #pragma unroll
    for (int mi = 0; mi < 4; ++mi) {
        #pragma unroll
        for (int r = 0; r < 4; ++r) {
            int rowl = wm + mi * 16 + q * 4 + r;
            int srow = row0 + rowl;
            if (srow < ne) {
                #pragma unroll
                for (int ni = 0; ni < 2; ++ni) {
                    float g = accg[mi][ni][r], u = accu[mi][ni][r];
                    float hv = g * u / (1.0f + __expf(-g));
                    hbuf[((size_t)e * CAP + srow) * FD + (nt << 6) + wn + ni * 16 + lr] = f2bf(hv);
                }
            }
        }
    }
}

// ---------- GEMM2: down-proj 128x128 tile, BK=64, double-buffered prefetch ----------
__global__ __launch_bounds__(256) void gemm_down(
        const u16* __restrict__ hbuf, const u16* __restrict__ wdT,
        const int* __restrict__ tok, const float* __restrict__ wts,
        const int* __restrict__ cnt, float* __restrict__ y) {
    int bid = blockIdx.x;
    int e  = bid >> 8;
    int mt = (bid >> 4) & 15;
    int nt = bid & 15;
    int ne = cnt[e]; if (ne > CAP) ne = CAP;
    int row0 = mt << 7;
    if (row0 >= ne) return;

    __shared__ u16 As[2][128 * 64];
    __shared__ u16 Bs[2][128 * 64];
    __shared__ int   toklds[128];
    __shared__ float wlds[128];

    int tid = threadIdx.x;
    if (tid < 128) {
        int r = row0 + tid;
        int ok = (r < ne);
        toklds[tid] = ok ? tok[e * CAP + r] : 0;
        wlds[tid]  = ok ? wts[e * CAP + r] : 0.0f;
    }

    const u16* ab = hbuf + ((size_t)e * CAP + row0) * FD;
    const u16* bb = wdT + ((size_t)e * HD + (nt << 7)) * FD;
    const u16* asrc[4]; const u16* bsrc[4];
    #pragma unroll
    for (int p = 0; p < 4; ++p) {
        int idx = tid + (p << 8);
        int r = idx >> 3;
        int c = (idx & 7) ^ (r & 7);            // XOR swizzle
        asrc[p] = ab + (size_t)r * FD + (c << 3);
        bsrc[p] = bb + (size_t)r * FD + (c << 3);
    }

    floatx4 acc[4][4];
    #pragma unroll
    for (int i = 0; i < 4; ++i)
        #pragma unroll
        for (int j = 0; j < 4; ++j) acc[i][j] = floatx4{0.f, 0.f, 0.f, 0.f};

    int l = tid & 63, w = tid >> 6;
    int wm = (w >> 1) << 6;
    int wn = (w & 1) << 6;
    int lr = l & 15, q = l >> 4;
    int sw = lr & 7;

    // prologue: stage tile 0 into buffer 0
    #pragma unroll
    for (int p = 0; p < 4; ++p) {
        cp16(asrc[p], &As[0][(tid + (p << 8)) << 3]);
        cp16(bsrc[p], &Bs[0][(tid + (p << 8)) << 3]);
    }
    __syncthreads();

    int cur = 0;
    for (int k0 = 64; k0 <= FD; k0 += 64) {
        if (k0 < FD) {
            int nx = cur ^ 1;
            #pragma unroll
            for (int p = 0; p < 4; ++p) {
                cp16(asrc[p] + k0, &As[nx][(tid + (p << 8)) << 3]);
                cp16(bsrc[p] + k0, &Bs[nx][(tid + (p << 8)) << 3]);
            }
        }
        #pragma unroll
        for (int kk = 0; kk < 2; ++kk) {
            int ch = ((kk << 2) + q) ^ sw;
            short8 af[4], bf[4];
            #pragma unroll
            for (int mi = 0; mi < 4; ++mi)
                af[mi] = *(const short8*)&As[cur][((wm + mi * 16 + lr) << 6) + (ch << 3)];
            #pragma unroll
            for (int ni = 0; ni < 4; ++ni)
                bf[ni] = *(const short8*)&Bs[cur][((wn + ni * 16 + lr) << 6) + (ch << 3)];
            #pragma unroll
            for (int mi = 0; mi < 4; ++mi)
                #pragma unroll
                for (int ni = 0; ni < 4; ++ni)
                    acc[mi][ni] = mfma_bf16(af[mi], bf[ni], acc[mi][ni]);
        }
        __syncthreads();
        cur ^= 1;
    }

    #pragma unroll
    for (int mi = 0; mi < 4; ++mi) {
        #pragma unroll
        for (int r = 0; r < 4; ++r) {
            int rowl = wm + mi * 16 + q * 4 + r;
            if (row0 + rowl < ne) {
                int   tv  = toklds[rowl];
                float wgt = wlds[rowl];
                float* yr = y + (size_t)tv * HD + (nt << 7) + wn + lr;
                #pragma unroll
                for (int ni = 0; ni < 4; ++ni)
                    atomicAdd(yr + ni * 16, wgt * acc[mi][ni][r]);
            }
        }
    }
}

// ---------- launch ----------
extern "C" void kernel_launch(void* const* d_in, const int* in_sizes, int n_in,
                              void* d_out, int out_size, void* d_ws, size_t ws_size,
                              hipStream_t stream) {
    const float* x      = (const float*)d_in[0];
    const float* gw     = (const float*)d_in[1];
    const float* w_gate = (const float*)d_in[2];
    const float* w_up   = (const float*)d_in[3];
    const float* w_down = (const float*)d_in[4];

    float* y      = (float*)d_out;
    float* logits = y + (size_t)NT * HD;

    char* ws = (char*)d_ws;
    const size_t SZ_WT = (size_t)NE * FD * HD * 2;            // 64 MB
    u16* wgT  = (u16*)(ws);                                   // later reused as wdT
    u16* wuT  = (u16*)(ws + SZ_WT);
    u16* xb   = (u16*)(ws + 2 * SZ_WT);
    u16* hbuf = (u16*)(ws + 2 * SZ_WT + (size_t)NT * HD * 2);
    char* tail = ws + 2 * SZ_WT + (size_t)NT * HD * 2 + (size_t)NE * CAP * FD * 2;
    int*   tok = (int*)(tail);
    float* wts = (float*)(tail + (size_t)NE * CAP * 4);
    int*   cnt = (int*)(tail + 2 * (size_t)NE * CAP * 4);

    hipMemsetAsync(d_out, 0, (size_t)out_size * sizeof(float), stream);
    hipMemsetAsync(cnt, 0, 256, stream);

    cvt_x_kernel<<<(NT * HD / 4) / 256, 256, 0, stream>>>(x, xb);
    transpose_cvt<<<dim3((HD / 64) * (FD / 64), NE), 256, 0, stream>>>(w_gate, wgT, HD, FD);
    transpose_cvt<<<dim3((HD / 64) * (FD / 64), NE), 256, 0, stream>>>(w_up,   wuT, HD, FD);
    router_kernel<<<NT, 64, 0, stream>>>(x, gw, logits, tok, wts, cnt);
    gemm_gateup<<<NE * 16 * 16, 256, 0, stream>>>(xb, wgT, wuT, tok, cnt, hbuf);
    // reuse wgT region for transposed w_down (stream-ordered after gemm_gateup)
    transpose_cvt<<<dim3((FD / 64) * (HD / 64), NE), 256, 0, stream>>>(w_down, wgT, FD, HD);
    gemm_down<<<NE * 16 * 16, 256, 0, stream>>>(hbuf, wgT, tok, wts, cnt, y);
}

// Round 3
// 979.600 us; speedup vs baseline: 1.0407x; 1.0289x over previous
//
#include <hip/hip_runtime.h>
#include <math.h>

typedef unsigned short u16;
typedef unsigned int   u32;
typedef __attribute__((ext_vector_type(8))) short short8;
typedef __attribute__((ext_vector_type(4))) float floatx4;
typedef __attribute__((ext_vector_type(4))) u16   u16x4;

#define NE   16      // experts
#define CAP  2048    // capacity per expert
#define HD   2048    // hidden
#define FD   1024    // intermediate
#define NT   4096    // tokens

// ---------- helpers ----------
__device__ __forceinline__ u16 f2bf(float f) {
    u32 u = __builtin_bit_cast(u32, f);
    u = (u + 0x7FFFu + ((u >> 16) & 1u)) >> 16;   // RNE
    return (u16)u;
}
__device__ __forceinline__ float bf2f(u16 v) {
    return __builtin_bit_cast(float, (u32)v << 16);
}

typedef const u32 __attribute__((address_space(1))) glb_u32;
typedef u32 __attribute__((address_space(3)))       lds_u32;

__device__ __forceinline__ void cp16(const void* g, void* l) {
    __builtin_amdgcn_global_load_lds((glb_u32*)g, (lds_u32*)l, 16, 0, 0);
}

__device__ __forceinline__ floatx4 mfma_bf16(short8 a, short8 b, floatx4 c) {
    return __builtin_amdgcn_mfma_f32_16x16x32_bf16(a, b, c, 0, 0, 0);
}

// XCD-contiguous swizzle: 4096 blocks, 8 XCDs. Default HW round-robin gives
// XCD = bid%8; remap so each XCD owns a contiguous 512-block chunk (= 2 experts):
// all blocks sharing an A-tile or B-panel land on the same XCD's L2.
__device__ __forceinline__ int xcd_swizzle(int bid0) {
    return ((bid0 & 7) << 9) | (bid0 >> 3);
}

// ---------- x -> bf16 ----------
__global__ void cvt_x_kernel(const float* __restrict__ x, u16* __restrict__ xb) {
    int i = blockIdx.x * 256 + threadIdx.x;
    float4 v = reinterpret_cast<const float4*>(x)[i];
    u16x4 o; o.x = f2bf(v.x); o.y = f2bf(v.y); o.z = f2bf(v.z); o.w = f2bf(v.w);
    reinterpret_cast<u16x4*>(xb)[i] = o;
}

// ---------- transpose + convert: in [R][Cc] fp32 -> out [Cc][R] bf16 (per expert) ----------
__global__ void transpose_cvt(const float* __restrict__ in, u16* __restrict__ out,
                              int R, int Cc) {
    __shared__ u16 tile[64][65];
    int e = blockIdx.y;
    int tilesC = Cc >> 6;
    int tr = blockIdx.x / tilesC;
    int tc = blockIdx.x - tr * tilesC;
    const float* ip = in + (size_t)e * R * Cc + (size_t)(tr * 64) * Cc + tc * 64;
    u16* op = out + (size_t)e * R * Cc + (size_t)(tc * 64) * R + tr * 64;
    int c  = threadIdx.x & 63;
    int r0 = threadIdx.x >> 6;
    #pragma unroll
    for (int i = 0; i < 16; ++i) {
        int r = r0 + (i << 2);
        tile[r][c] = f2bf(ip[(size_t)r * Cc + c]);
    }
    __syncthreads();
    int rr = threadIdx.x & 63;
    int c0 = threadIdx.x >> 6;
    #pragma unroll
    for (int i = 0; i < 16; ++i) {
        int cc = c0 + (i << 2);
        op[(size_t)cc * R + rr] = tile[rr][cc];
    }
}

// ---------- router: fp64-exact logits, top-4, softmax, dispatch ----------
// Records per-slot token id + rank, and per-token weights (for atomic-free combine).
__global__ void router_kernel(const float* __restrict__ x, const float* __restrict__ gw,
                              float* __restrict__ logits, int* __restrict__ tok,
                              int* __restrict__ rnk, float* __restrict__ wtok,
                              int* __restrict__ cnt) {
    int t = blockIdx.x;
    int l = threadIdx.x;      // 0..63
    const float* xr = x + (size_t)t * HD;
    double acc[NE];
    #pragma unroll
    for (int e = 0; e < NE; ++e) acc[e] = 0.0;
    for (int i = 0; i < HD / 64; ++i) {
        float xv = xr[l + (i << 6)];
        const float* g = gw + (size_t)(l + (i << 6)) * NE;
        #pragma unroll
        for (int e = 0; e < NE; ++e) acc[e] += (double)xv * (double)g[e];
    }
    #pragma unroll
    for (int e = 0; e < NE; ++e) {
        double v = acc[e];
        #pragma unroll
        for (int off = 1; off < 64; off <<= 1) v += __shfl_xor(v, off, 64);
        acc[e] = v;
    }
    if (l == 0) {
        #pragma unroll
        for (int e = 0; e < NE; ++e) logits[(size_t)t * NE + e] = (float)acc[e];
        int bi[4]; double bv[4];
        u32 used = 0;
        for (int k = 0; k < 4; ++k) {
            int best = 0; double bvv = -1e300;
            for (int e = 0; e < NE; ++e)
                if (!((used >> e) & 1u) && acc[e] > bvv) { bvv = acc[e]; best = e; }
            bi[k] = best; bv[k] = bvv; used |= 1u << best;
        }
        double s = 0.0, wv[4];
        for (int k = 0; k < 4; ++k) { wv[k] = exp(bv[k] - bv[0]); s += wv[k]; }
        for (int k = 0; k < 4; ++k) {
            int e = bi[k];
            int pos = atomicAdd(&cnt[e], 1);
            wtok[t * 4 + k] = (float)(wv[k] / s);
            if (pos < CAP) {
                tok[e * CAP + pos] = t;
                rnk[e * CAP + pos] = k;
            }
        }
    }
}

// ---------- GEMM1: fused gate+up, 128x(64+64) tile, BK=64, double-buffered prefetch ----------
__global__ __launch_bounds__(256) void gemm_gateup(
        const u16* __restrict__ xb, const u16* __restrict__ wgT, const u16* __restrict__ wuT,
        const int* __restrict__ tok, const int* __restrict__ cnt, u16* __restrict__ hbuf) {
    int bid = xcd_swizzle(blockIdx.x);
    int e  = bid >> 8;
    int mt = (bid >> 4) & 15;
    int nt = bid & 15;
    int ne = cnt[e]; if (ne > CAP) ne = CAP;
    int row0 = mt << 7;
    if (row0 >= ne) return;

    __shared__ u16 As[2][128 * 64];
    __shared__ u16 Bg[2][64 * 64];
    __shared__ u16 Bu[2][64 * 64];
    __shared__ int toklds[128];

    int tid = threadIdx.x;
    if (tid < 128) {
        int r = row0 + tid;
        toklds[tid] = tok[e * CAP + (r < ne ? r : 0)];
    }
    __syncthreads();

    const u16* asrc[4];
    #pragma unroll
    for (int p = 0; p < 4; ++p) {
        int idx = tid + (p << 8);
        int r = idx >> 3;
        int c = (idx & 7) ^ (r & 7);            // XOR swizzle
        asrc[p] = xb + (size_t)toklds[r] * HD + (c << 3);
    }
    const u16* bgb = wgT + ((size_t)e * FD + (nt << 6)) * HD;
    const u16* bub = wuT + ((size_t)e * FD + (nt << 6)) * HD;
    const u16* bgsrc[2]; const u16* busrc[2];
    #pragma unroll
    for (int p = 0; p < 2; ++p) {
        int idx = tid + (p << 8);
        int r = idx >> 3;
        int c = (idx & 7) ^ (r & 7);            // XOR swizzle
        bgsrc[p] = bgb + (size_t)r * HD + (c << 3);
        busrc[p] = bub + (size_t)r * HD + (c << 3);
    }

    floatx4 accg[4][2], accu[4][2];
    #pragma unroll
    for (int i = 0; i < 4; ++i)
        #pragma unroll
        for (int j = 0; j < 2; ++j) {
            accg[i][j] = floatx4{0.f, 0.f, 0.f, 0.f};
            accu[i][j] = floatx4{0.f, 0.f, 0.f, 0.f};
        }

    int l = tid & 63, w = tid >> 6;
    int wm = (w >> 1) << 6;   // 0 / 64
    int wn = (w & 1) << 5;    // 0 / 32
    int lr = l & 15, q = l >> 4;
    int sw = lr & 7;          // swizzle key for fragment reads

    // prologue: stage tile 0 into buffer 0
    #pragma unroll
    for (int p = 0; p < 4; ++p) cp16(asrc[p], &As[0][(tid + (p << 8)) << 3]);
    #pragma unroll
    for (int p = 0; p < 2; ++p) {
        cp16(bgsrc[p], &Bg[0][(tid + (p << 8)) << 3]);
        cp16(busrc[p], &Bu[0][(tid + (p << 8)) << 3]);
    }
    __syncthreads();

    int cur = 0;
    for (int k0 = 64; k0 <= HD; k0 += 64) {
        if (k0 < HD) {
            int nx = cur ^ 1;
            #pragma unroll
            for (int p = 0; p < 4; ++p) cp16(asrc[p] + k0, &As[nx][(tid + (p << 8)) << 3]);
            #pragma unroll
            for (int p = 0; p < 2; ++p) {
                cp16(bgsrc[p] + k0, &Bg[nx][(tid + (p << 8)) << 3]);
                cp16(busrc[p] + k0, &Bu[nx][(tid + (p << 8)) << 3]);
            }
        }
        #pragma unroll
        for (int kk = 0; kk < 2; ++kk) {
            int ch = ((kk << 2) + q) ^ sw;      // swizzled chunk
            short8 af[4], bg[2], bu[2];
            #pragma unroll
            for (int mi = 0; mi < 4; ++mi)
                af[mi] = *(const short8*)&As[cur][((wm + mi * 16 + lr) << 6) + (ch << 3)];
            #pragma unroll
            for (int ni = 0; ni < 2; ++ni) {
                bg[ni] = *(const short8*)&Bg[cur][((wn + ni * 16 + lr) << 6) + (ch << 3)];
                bu[ni] = *(const short8*)&Bu[cur][((wn + ni * 16 + lr) << 6) + (ch << 3)];
            }
            #pragma unroll
            for (int mi = 0; mi < 4; ++mi)
                #pragma unroll
                for (int ni = 0; ni < 2; ++ni) {
                    accg[mi][ni] = mfma_bf16(af[mi], bg[ni], accg[mi][ni]);
                    accu[mi][ni] = mfma_bf16(af[mi], bu[ni], accu[mi][ni]);
                }
        }
        __syncthreads();
        cur ^= 1;
    }

    // epilogue: h = silu(g)*u, bf16 store
    #pragma unroll
    for (int mi = 0; mi < 4; ++mi) {
        #pragma unroll
        for (int r = 0; r < 4; ++r) {
            int rowl = wm + mi * 16 + q * 4 + r;
            int srow = row0 + rowl;
            if (srow < ne) {
                #pragma unroll
                for (int ni = 0; ni < 2; ++ni) {
                    float g = accg[mi][ni][r], u = accu[mi][ni][r];
                    float hv = g * u / (1.0f + __expf(-g));
                    hbuf[((size_t)e * CAP + srow) * FD + (nt << 6) + wn + ni * 16 + lr] = f2bf(hv);
                }
            }
        }
    }
}

// ---------- GEMM2: down-proj 128x128 tile, BK=64, atomic-free epilogue ----------
// Writes unweighted bf16 slot outputs into yk[rank][token][H]; combine sums them.
__global__ __launch_bounds__(256) void gemm_down(
        const u16* __restrict__ hbuf, const u16* __restrict__ wdT,
        const int* __restrict__ tok, const int* __restrict__ rnk,
        const int* __restrict__ cnt, u16* __restrict__ yk) {
    int bid = xcd_swizzle(blockIdx.x);
    int e  = bid >> 8;
    int mt = (bid >> 4) & 15;
    int nt = bid & 15;
    int ne = cnt[e]; if (ne > CAP) ne = CAP;
    int row0 = mt << 7;
    if (row0 >= ne) return;

    __shared__ u16 As[2][128 * 64];
    __shared__ u16 Bs[2][128 * 64];
    __shared__ int toklds[128];
    __shared__ int rklds[128];

    int tid = threadIdx.x;
    if (tid < 128) {
        int r = row0 + tid;
        int ok = (r < ne);
        toklds[tid] = ok ? tok[e * CAP + r] : 0;
        rklds[tid]  = ok ? rnk[e * CAP + r] : 0;
    }

    const u16* ab = hbuf + ((size_t)e * CAP + row0) * FD;
    const u16* bb = wdT + ((size_t)e * HD + (nt << 7)) * FD;
    const u16* asrc[4]; const u16* bsrc[4];
    #pragma unroll
    for (int p = 0; p < 4; ++p) {
        int idx = tid + (p << 8);
        int r = idx >> 3;
        int c = (idx & 7) ^ (r & 7);            // XOR swizzle
        asrc[p] = ab + (size_t)r * FD + (c << 3);
        bsrc[p] = bb + (size_t)r * FD + (c << 3);
    }

    floatx4 acc[4][4];
    #pragma unroll
    for (int i = 0; i < 4; ++i)
        #pragma unroll
        for (int j = 0; j < 4; ++j) acc[i][j] = floatx4{0.f, 0.f, 0.f, 0.f};

    int l = tid & 63, w = tid >> 6;
    int wm = (w >> 1) << 6;
    int wn = (w & 1) << 6;
    int lr = l & 15, q = l >> 4;
    int sw = lr & 7;

    // prologue: stage tile 0 into buffer 0
    #pragma unroll
    for (int p = 0; p < 4; ++p) {
        cp16(asrc[p], &As[0][(tid + (p << 8)) << 3]);
        cp16(bsrc[p], &Bs[0][(tid + (p << 8)) << 3]);
    }
    __syncthreads();

    int cur = 0;
    for (int k0 = 64; k0 <= FD; k0 += 64) {
        if (k0 < FD) {
            int nx = cur ^ 1;
            #pragma unroll
            for (int p = 0; p < 4; ++p) {
                cp16(asrc[p] + k0, &As[nx][(tid + (p << 8)) << 3]);
                cp16(bsrc[p] + k0, &Bs[nx][(tid + (p << 8)) << 3]);
            }
        }
        #pragma unroll
        for (int kk = 0; kk < 2; ++kk) {
            int ch = ((kk << 2) + q) ^ sw;
            short8 af[4], bf[4];
            #pragma unroll
            for (int mi = 0; mi < 4; ++mi)
                af[mi] = *(const short8*)&As[cur][((wm + mi * 16 + lr) << 6) + (ch << 3)];
            #pragma unroll
            for (int ni = 0; ni < 4; ++ni)
                bf[ni] = *(const short8*)&Bs[cur][((wn + ni * 16 + lr) << 6) + (ch << 3)];
            #pragma unroll
            for (int mi = 0; mi < 4; ++mi)
                #pragma unroll
                for (int ni = 0; ni < 4; ++ni)
                    acc[mi][ni] = mfma_bf16(af[mi], bf[ni], acc[mi][ni]);
        }
        __syncthreads();
        cur ^= 1;
    }

    #pragma unroll
    for (int mi = 0; mi < 4; ++mi) {
        #pragma unroll
        for (int r = 0; r < 4; ++r) {
            int rowl = wm + mi * 16 + q * 4 + r;
            if (row0 + rowl < ne) {
                int tv = toklds[rowl];
                int rk = rklds[rowl];
                u16* yr = yk + ((size_t)rk * NT + tv) * HD + (nt << 7) + wn + lr;
                #pragma unroll
                for (int ni = 0; ni < 4; ++ni)
                    yr[ni * 16] = f2bf(acc[mi][ni][r]);
            }
        }
    }
}

// ---------- combine: y[t] = sum_k wtok[t][k] * yk[k][t]  (fully overwrites y) ----------
__global__ __launch_bounds__(256) void combine_kernel(
        const u16* __restrict__ yk, const float* __restrict__ wtok,
        float* __restrict__ y) {
    int t = blockIdx.x;
    int h0 = threadIdx.x << 3;     // 8 elements per thread
    float wk[4];
    #pragma unroll
    for (int k = 0; k < 4; ++k) wk[k] = wtok[t * 4 + k];
    float acc[8];
    #pragma unroll
    for (int j = 0; j < 8; ++j) acc[j] = 0.f;
    #pragma unroll
    for (int k = 0; k < 4; ++k) {
        short8 v = *reinterpret_cast<const short8*>(&yk[((size_t)k * NT + t) * HD + h0]);
        #pragma unroll
        for (int j = 0; j < 8; ++j) acc[j] += wk[k] * bf2f((u16)v[j]);
    }
    float4 o0{acc[0], acc[1], acc[2], acc[3]};
    float4 o1{acc[4], acc[5], acc[6], acc[7]};
    float4* yo = reinterpret_cast<float4*>(y + (size_t)t * HD + h0);
    yo[0] = o0; yo[1] = o1;
}

// ---------- launch ----------
extern "C" void kernel_launch(void* const* d_in, const int* in_sizes, int n_in,
                              void* d_out, int out_size, void* d_ws, size_t ws_size,
                              hipStream_t stream) {
    const float* x      = (const float*)d_in[0];
    const float* gw     = (const float*)d_in[1];
    const float* w_gate = (const float*)d_in[2];
    const float* w_up   = (const float*)d_in[3];
    const float* w_down = (const float*)d_in[4];

    float* y      = (float*)d_out;
    float* logits = y + (size_t)NT * HD;

    char* ws = (char*)d_ws;
    const size_t SZ_WT = (size_t)NE * FD * HD * 2;            // 64 MB
    u16* wgT  = (u16*)(ws);                                   // later reused as wdT
    u16* wuT  = (u16*)(ws + SZ_WT);
    u16* xb   = (u16*)(ws + 2 * SZ_WT);
    u16* hbuf = (u16*)(ws + 2 * SZ_WT + (size_t)NT * HD * 2);
    // yk[4][NT][HD] bf16 (67 MB) overlays wuT (64 MB) + head of xb (3 MB);
    // both are dead by the time gemm_down runs (stream-ordered after gemm_gateup).
    u16* yk   = (u16*)(ws + SZ_WT);
    char* tail = ws + 2 * SZ_WT + (size_t)NT * HD * 2 + (size_t)NE * CAP * FD * 2;
    int*   tok  = (int*)(tail);
    int*   rnk  = (int*)(tail + (size_t)NE * CAP * 4);
    float* wtok = (float*)(tail + 2 * (size_t)NE * CAP * 4);
    int*   cnt  = (int*)(tail + 2 * (size_t)NE * CAP * 4 + (size_t)NT * 4 * 4);

    hipMemsetAsync(cnt, 0, 256, stream);

    cvt_x_kernel<<<(NT * HD / 4) / 256, 256, 0, stream>>>(x, xb);
    transpose_cvt<<<dim3((HD / 64) * (FD / 64), NE), 256, 0, stream>>>(w_gate, wgT, HD, FD);
    transpose_cvt<<<dim3((HD / 64) * (FD / 64), NE), 256, 0, stream>>>(w_up,   wuT, HD, FD);
    router_kernel<<<NT, 64, 0, stream>>>(x, gw, logits, tok, rnk, wtok, cnt);
    gemm_gateup<<<NE * 16 * 16, 256, 0, stream>>>(xb, wgT, wuT, tok, cnt, hbuf);
    // reuse wgT region for transposed w_down (stream-ordered after gemm_gateup)
    transpose_cvt<<<dim3((FD / 64) * (HD / 64), NE), 256, 0, stream>>>(w_down, wgT, FD, HD);
    gemm_down<<<NE * 16 * 16, 256, 0, stream>>>(hbuf, wgT, tok, rnk, cnt, yk);
    combine_kernel<<<NT, 256, 0, stream>>>(yk, wtok, y);
}

// Round 4
// 876.191 us; speedup vs baseline: 1.1636x; 1.1180x over previous
//
#include <hip/hip_runtime.h>
#include <math.h>

typedef unsigned short u16;
typedef unsigned int   u32;
typedef unsigned long long u64;
typedef __attribute__((ext_vector_type(8))) short short8;
typedef __attribute__((ext_vector_type(4))) float floatx4;
typedef __attribute__((ext_vector_type(4))) u16   u16x4;

#define NE   16      // experts
#define CAP  2048    // capacity per expert
#define HD   2048    // hidden
#define FD   1024    // intermediate
#define NT   4096    // tokens

// ---------- helpers ----------
__device__ __forceinline__ u16 f2bf(float f) {
    u32 u = __builtin_bit_cast(u32, f);
    u = (u + 0x7FFFu + ((u >> 16) & 1u)) >> 16;   // RNE
    return (u16)u;
}
__device__ __forceinline__ float bf2f(u16 v) {
    return __builtin_bit_cast(float, (u32)v << 16);
}

typedef const u32 __attribute__((address_space(1))) glb_u32;
typedef u32 __attribute__((address_space(3)))       lds_u32;

__device__ __forceinline__ void cp16(const void* g, void* l) {
    __builtin_amdgcn_global_load_lds((glb_u32*)g, (lds_u32*)l, 16, 0, 0);
}

__device__ __forceinline__ floatx4 mfma_bf16(short8 a, short8 b, floatx4 c) {
    return __builtin_amdgcn_mfma_f32_16x16x32_bf16(a, b, c, 0, 0, 0);
}

// XCD-contiguous swizzle: 4096 blocks, 8 XCDs. Default HW round-robin gives
// XCD = bid%8; remap so each XCD owns a contiguous 512-block chunk (= 2 experts).
__device__ __forceinline__ int xcd_swizzle(int bid0) {
    return ((bid0 & 7) << 9) | (bid0 >> 3);
}

// ---------- x -> bf16 ----------
__global__ void cvt_x_kernel(const float* __restrict__ x, u16* __restrict__ xb) {
    int i = blockIdx.x * 256 + threadIdx.x;
    float4 v = reinterpret_cast<const float4*>(x)[i];
    u16x4 o; o.x = f2bf(v.x); o.y = f2bf(v.y); o.z = f2bf(v.z); o.w = f2bf(v.w);
    reinterpret_cast<u16x4*>(xb)[i] = o;
}

// ---------- transpose + convert: in [R][Cc] fp32 -> out [Cc][R] bf16 (per expert) ----------
__global__ void transpose_cvt(const float* __restrict__ in, u16* __restrict__ out,
                              int R, int Cc) {
    __shared__ u16 tile[64][65];
    int e = blockIdx.y;
    int tilesC = Cc >> 6;
    int tr = blockIdx.x / tilesC;
    int tc = blockIdx.x - tr * tilesC;
    const float* ip = in + (size_t)e * R * Cc + (size_t)(tr * 64) * Cc + tc * 64;
    u16* op = out + (size_t)e * R * Cc + (size_t)(tc * 64) * R + tr * 64;
    int c  = threadIdx.x & 63;
    int r0 = threadIdx.x >> 6;
    #pragma unroll
    for (int i = 0; i < 16; ++i) {
        int r = r0 + (i << 2);
        tile[r][c] = f2bf(ip[(size_t)r * Cc + c]);
    }
    __syncthreads();
    int rr = threadIdx.x & 63;
    int c0 = threadIdx.x >> 6;
    #pragma unroll
    for (int i = 0; i < 16; ++i) {
        int cc = c0 + (i << 2);
        op[(size_t)cc * R + rr] = tile[rr][cc];
    }
}

// ---------- router phase 1: fp64-exact logits, top-4, softmax. NO atomics. ----------
__global__ void router_logits(const float* __restrict__ x, const float* __restrict__ gw,
                              float* __restrict__ logits, int* __restrict__ topi,
                              float* __restrict__ wtok) {
    int t = blockIdx.x;
    int l = threadIdx.x;      // 0..63
    const float* xr = x + (size_t)t * HD;
    double acc[NE];
    #pragma unroll
    for (int e = 0; e < NE; ++e) acc[e] = 0.0;
    for (int i = 0; i < HD / 64; ++i) {
        float xv = xr[l + (i << 6)];
        const float* g = gw + (size_t)(l + (i << 6)) * NE;
        #pragma unroll
        for (int e = 0; e < NE; ++e) acc[e] += (double)xv * (double)g[e];
    }
    #pragma unroll
    for (int e = 0; e < NE; ++e) {
        double v = acc[e];
        #pragma unroll
        for (int off = 1; off < 64; off <<= 1) v += __shfl_xor(v, off, 64);
        acc[e] = v;
    }
    if (l == 0) {
        #pragma unroll
        for (int e = 0; e < NE; ++e) logits[(size_t)t * NE + e] = (float)acc[e];
        int bi[4]; double bv[4];
        u32 used = 0;
        for (int k = 0; k < 4; ++k) {
            int best = 0; double bvv = -1e300;
            for (int e = 0; e < NE; ++e)
                if (!((used >> e) & 1u) && acc[e] > bvv) { bvv = acc[e]; best = e; }
            bi[k] = best; bv[k] = bvv; used |= 1u << best;
        }
        double s = 0.0, wv[4];
        for (int k = 0; k < 4; ++k) { wv[k] = exp(bv[k] - bv[0]); s += wv[k]; }
        for (int k = 0; k < 4; ++k) {
            topi[t * 4 + k] = bi[k];
            wtok[t * 4 + k] = (float)(wv[k] / s);
        }
    }
}

// ---------- router phase 2: atomic-free dispatch ----------
// One wave per expert; scans all T*K slots in order, assigns positions by
// ballot+prefix. Position order == reference's slot-order cumsum exactly.
__global__ void dispatch_kernel(const int* __restrict__ topi, int* __restrict__ tok,
                                int* __restrict__ rnk, int* __restrict__ cnt) {
    int e = blockIdx.x;       // 0..15
    int l = threadIdx.x;      // 0..63
    u64 lanebit_m1 = (l == 0) ? 0ull : (~0ull >> (64 - l));
    int base = 0;
    #pragma unroll 4
    for (int s0 = 0; s0 < NT * 4; s0 += 64) {
        int s = s0 + l;
        int ex = topi[s];
        u64 m = __ballot(ex == e);
        if (ex == e) {
            int pos = base + __popcll(m & lanebit_m1);
            if (pos < CAP) {
                tok[e * CAP + pos] = s >> 2;
                rnk[e * CAP + pos] = s & 3;
            }
        }
        base += __popcll(m);
    }
    if (l == 0) cnt[e] = base;
}

// ---------- GEMM1: fused gate+up, 128x(64+64) tile, BK=64, double-buffered prefetch ----------
__global__ __launch_bounds__(256) void gemm_gateup(
        const u16* __restrict__ xb, const u16* __restrict__ wgT, const u16* __restrict__ wuT,
        const int* __restrict__ tok, const int* __restrict__ cnt, u16* __restrict__ hbuf) {
    int bid = xcd_swizzle(blockIdx.x);
    int e  = bid >> 8;
    int mt = (bid >> 4) & 15;
    int nt = bid & 15;
    int ne = cnt[e]; if (ne > CAP) ne = CAP;
    int row0 = mt << 7;
    if (row0 >= ne) return;

    __shared__ u16 As[2][128 * 64];
    __shared__ u16 Bg[2][64 * 64];
    __shared__ u16 Bu[2][64 * 64];
    __shared__ int toklds[128];

    int tid = threadIdx.x;
    if (tid < 128) {
        int r = row0 + tid;
        toklds[tid] = tok[e * CAP + (r < ne ? r : 0)];
    }
    __syncthreads();

    const u16* asrc[4];
    #pragma unroll
    for (int p = 0; p < 4; ++p) {
        int idx = tid + (p << 8);
        int r = idx >> 3;
        int c = (idx & 7) ^ (r & 7);            // XOR swizzle
        asrc[p] = xb + (size_t)toklds[r] * HD + (c << 3);
    }
    const u16* bgb = wgT + ((size_t)e * FD + (nt << 6)) * HD;
    const u16* bub = wuT + ((size_t)e * FD + (nt << 6)) * HD;
    const u16* bgsrc[2]; const u16* busrc[2];
    #pragma unroll
    for (int p = 0; p < 2; ++p) {
        int idx = tid + (p << 8);
        int r = idx >> 3;
        int c = (idx & 7) ^ (r & 7);            // XOR swizzle
        bgsrc[p] = bgb + (size_t)r * HD + (c << 3);
        busrc[p] = bub + (size_t)r * HD + (c << 3);
    }

    floatx4 accg[4][2], accu[4][2];
    #pragma unroll
    for (int i = 0; i < 4; ++i)
        #pragma unroll
        for (int j = 0; j < 2; ++j) {
            accg[i][j] = floatx4{0.f, 0.f, 0.f, 0.f};
            accu[i][j] = floatx4{0.f, 0.f, 0.f, 0.f};
        }

    int l = tid & 63, w = tid >> 6;
    int wm = (w >> 1) << 6;   // 0 / 64
    int wn = (w & 1) << 5;    // 0 / 32
    int lr = l & 15, q = l >> 4;
    int sw = lr & 7;          // swizzle key for fragment reads

    // prologue: stage tile 0 into buffer 0
    #pragma unroll
    for (int p = 0; p < 4; ++p) cp16(asrc[p], &As[0][(tid + (p << 8)) << 3]);
    #pragma unroll
    for (int p = 0; p < 2; ++p) {
        cp16(bgsrc[p], &Bg[0][(tid + (p << 8)) << 3]);
        cp16(busrc[p], &Bu[0][(tid + (p << 8)) << 3]);
    }
    __syncthreads();

    int cur = 0;
    for (int k0 = 64; k0 <= HD; k0 += 64) {
        if (k0 < HD) {
            int nx = cur ^ 1;
            #pragma unroll
            for (int p = 0; p < 4; ++p) cp16(asrc[p] + k0, &As[nx][(tid + (p << 8)) << 3]);
            #pragma unroll
            for (int p = 0; p < 2; ++p) {
                cp16(bgsrc[p] + k0, &Bg[nx][(tid + (p << 8)) << 3]);
                cp16(busrc[p] + k0, &Bu[nx][(tid + (p << 8)) << 3]);
            }
        }
        #pragma unroll
        for (int kk = 0; kk < 2; ++kk) {
            int ch = ((kk << 2) + q) ^ sw;      // swizzled chunk
            short8 af[4], bg[2], bu[2];
            #pragma unroll
            for (int mi = 0; mi < 4; ++mi)
                af[mi] = *(const short8*)&As[cur][((wm + mi * 16 + lr) << 6) + (ch << 3)];
            #pragma unroll
            for (int ni = 0; ni < 2; ++ni) {
                bg[ni] = *(const short8*)&Bg[cur][((wn + ni * 16 + lr) << 6) + (ch << 3)];
                bu[ni] = *(const short8*)&Bu[cur][((wn + ni * 16 + lr) << 6) + (ch << 3)];
            }
            #pragma unroll
            for (int mi = 0; mi < 4; ++mi)
                #pragma unroll
                for (int ni = 0; ni < 2; ++ni) {
                    accg[mi][ni] = mfma_bf16(af[mi], bg[ni], accg[mi][ni]);
                    accu[mi][ni] = mfma_bf16(af[mi], bu[ni], accu[mi][ni]);
                }
        }
        __syncthreads();
        cur ^= 1;
    }

    // epilogue: h = silu(g)*u, bf16 store
    #pragma unroll
    for (int mi = 0; mi < 4; ++mi) {
        #pragma unroll
        for (int r = 0; r < 4; ++r) {
            int rowl = wm + mi * 16 + q * 4 + r;
            int srow = row0 + rowl;
            if (srow < ne) {
                #pragma unroll
                for (int ni = 0; ni < 2; ++ni) {
                    float g = accg[mi][ni][r], u = accu[mi][ni][r];
                    float hv = g * u / (1.0f + __expf(-g));
                    hbuf[((size_t)e * CAP + srow) * FD + (nt << 6) + wn + ni * 16 + lr] = f2bf(hv);
                }
            }
        }
    }
}

// ---------- GEMM2: down-proj 128x128 tile, BK=64, atomic-free epilogue ----------
__global__ __launch_bounds__(256) void gemm_down(
        const u16* __restrict__ hbuf, const u16* __restrict__ wdT,
        const int* __restrict__ tok, const int* __restrict__ rnk,
        const int* __restrict__ cnt, u16* __restrict__ yk) {
    int bid = xcd_swizzle(blockIdx.x);
    int e  = bid >> 8;
    int mt = (bid >> 4) & 15;
    int nt = bid & 15;
    int ne = cnt[e]; if (ne > CAP) ne = CAP;
    int row0 = mt << 7;
    if (row0 >= ne) return;

    __shared__ u16 As[2][128 * 64];
    __shared__ u16 Bs[2][128 * 64];
    __shared__ int toklds[128];
    __shared__ int rklds[128];

    int tid = threadIdx.x;
    if (tid < 128) {
        int r = row0 + tid;
        int ok = (r < ne);
        toklds[tid] = ok ? tok[e * CAP + r] : 0;
        rklds[tid]  = ok ? rnk[e * CAP + r] : 0;
    }

    const u16* ab = hbuf + ((size_t)e * CAP + row0) * FD;
    const u16* bb = wdT + ((size_t)e * HD + (nt << 7)) * FD;
    const u16* asrc[4]; const u16* bsrc[4];
    #pragma unroll
    for (int p = 0; p < 4; ++p) {
        int idx = tid + (p << 8);
        int r = idx >> 3;
        int c = (idx & 7) ^ (r & 7);            // XOR swizzle
        asrc[p] = ab + (size_t)r * FD + (c << 3);
        bsrc[p] = bb + (size_t)r * FD + (c << 3);
    }

    floatx4 acc[4][4];
    #pragma unroll
    for (int i = 0; i < 4; ++i)
        #pragma unroll
        for (int j = 0; j < 4; ++j) acc[i][j] = floatx4{0.f, 0.f, 0.f, 0.f};

    int l = tid & 63, w = tid >> 6;
    int wm = (w >> 1) << 6;
    int wn = (w & 1) << 6;
    int lr = l & 15, q = l >> 4;
    int sw = lr & 7;

    // prologue: stage tile 0 into buffer 0
    #pragma unroll
    for (int p = 0; p < 4; ++p) {
        cp16(asrc[p], &As[0][(tid + (p << 8)) << 3]);
        cp16(bsrc[p], &Bs[0][(tid + (p << 8)) << 3]);
    }
    __syncthreads();

    int cur = 0;
    for (int k0 = 64; k0 <= FD; k0 += 64) {
        if (k0 < FD) {
            int nx = cur ^ 1;
            #pragma unroll
            for (int p = 0; p < 4; ++p) {
                cp16(asrc[p] + k0, &As[nx][(tid + (p << 8)) << 3]);
                cp16(bsrc[p] + k0, &Bs[nx][(tid + (p << 8)) << 3]);
            }
        }
        #pragma unroll
        for (int kk = 0; kk < 2; ++kk) {
            int ch = ((kk << 2) + q) ^ sw;
            short8 af[4], bf[4];
            #pragma unroll
            for (int mi = 0; mi < 4; ++mi)
                af[mi] = *(const short8*)&As[cur][((wm + mi * 16 + lr) << 6) + (ch << 3)];
            #pragma unroll
            for (int ni = 0; ni < 4; ++ni)
                bf[ni] = *(const short8*)&Bs[cur][((wn + ni * 16 + lr) << 6) + (ch << 3)];
            #pragma unroll
            for (int mi = 0; mi < 4; ++mi)
                #pragma unroll
                for (int ni = 0; ni < 4; ++ni)
                    acc[mi][ni] = mfma_bf16(af[mi], bf[ni], acc[mi][ni]);
        }
        __syncthreads();
        cur ^= 1;
    }

    #pragma unroll
    for (int mi = 0; mi < 4; ++mi) {
        #pragma unroll
        for (int r = 0; r < 4; ++r) {
            int rowl = wm + mi * 16 + q * 4 + r;
            if (row0 + rowl < ne) {
                int tv = toklds[rowl];
                int rk = rklds[rowl];
                u16* yr = yk + ((size_t)rk * NT + tv) * HD + (nt << 7) + wn + lr;
                #pragma unroll
                for (int ni = 0; ni < 4; ++ni)
                    yr[ni * 16] = f2bf(acc[mi][ni][r]);
            }
        }
    }
}

// ---------- combine: y[t] = sum_k wtok[t][k] * yk[k][t]  (fully overwrites y) ----------
__global__ __launch_bounds__(256) void combine_kernel(
        const u16* __restrict__ yk, const float* __restrict__ wtok,
        float* __restrict__ y) {
    int t = blockIdx.x;
    int h0 = threadIdx.x << 3;     // 8 elements per thread
    float wk[4];
    #pragma unroll
    for (int k = 0; k < 4; ++k) wk[k] = wtok[t * 4 + k];
    float acc[8];
    #pragma unroll
    for (int j = 0; j < 8; ++j) acc[j] = 0.f;
    #pragma unroll
    for (int k = 0; k < 4; ++k) {
        short8 v = *reinterpret_cast<const short8*>(&yk[((size_t)k * NT + t) * HD + h0]);
        #pragma unroll
        for (int j = 0; j < 8; ++j) acc[j] += wk[k] * bf2f((u16)v[j]);
    }
    float4 o0{acc[0], acc[1], acc[2], acc[3]};
    float4 o1{acc[4], acc[5], acc[6], acc[7]};
    float4* yo = reinterpret_cast<float4*>(y + (size_t)t * HD + h0);
    yo[0] = o0; yo[1] = o1;
}

// ---------- launch ----------
extern "C" void kernel_launch(void* const* d_in, const int* in_sizes, int n_in,
                              void* d_out, int out_size, void* d_ws, size_t ws_size,
                              hipStream_t stream) {
    const float* x      = (const float*)d_in[0];
    const float* gw     = (const float*)d_in[1];
    const float* w_gate = (const float*)d_in[2];
    const float* w_up   = (const float*)d_in[3];
    const float* w_down = (const float*)d_in[4];

    float* y      = (float*)d_out;
    float* logits = y + (size_t)NT * HD;

    char* ws = (char*)d_ws;
    const size_t SZ_WT = (size_t)NE * FD * HD * 2;            // 64 MB
    u16* wgT  = (u16*)(ws);                                   // later reused as wdT
    u16* wuT  = (u16*)(ws + SZ_WT);
    u16* xb   = (u16*)(ws + 2 * SZ_WT);
    u16* hbuf = (u16*)(ws + 2 * SZ_WT + (size_t)NT * HD * 2);
    // yk[4][NT][HD] bf16 (67 MB) overlays wuT (64 MB) + head of xb (3 MB);
    // both are dead by the time gemm_down runs (stream-ordered after gemm_gateup).
    u16* yk   = (u16*)(ws + SZ_WT);
    char* tail = ws + 2 * SZ_WT + (size_t)NT * HD * 2 + (size_t)NE * CAP * FD * 2;
    int*   tok  = (int*)(tail);
    int*   rnk  = (int*)(tail + (size_t)NE * CAP * 4);
    float* wtok = (float*)(tail + 2 * (size_t)NE * CAP * 4);
    int*   topi = (int*)(tail + 2 * (size_t)NE * CAP * 4 + (size_t)NT * 4 * 4);
    int*   cnt  = (int*)(tail + 2 * (size_t)NE * CAP * 4 + 2 * (size_t)NT * 4 * 4);

    cvt_x_kernel<<<(NT * HD / 4) / 256, 256, 0, stream>>>(x, xb);
    transpose_cvt<<<dim3((HD / 64) * (FD / 64), NE), 256, 0, stream>>>(w_gate, wgT, HD, FD);
    transpose_cvt<<<dim3((HD / 64) * (FD / 64), NE), 256, 0, stream>>>(w_up,   wuT, HD, FD);
    router_logits<<<NT, 64, 0, stream>>>(x, gw, logits, topi, wtok);
    dispatch_kernel<<<NE, 64, 0, stream>>>(topi, tok, rnk, cnt);
    gemm_gateup<<<NE * 16 * 16, 256, 0, stream>>>(xb, wgT, wuT, tok, cnt, hbuf);
    // reuse wgT region for transposed w_down (stream-ordered after gemm_gateup)
    transpose_cvt<<<dim3((FD / 64) * (HD / 64), NE), 256, 0, stream>>>(w_down, wgT, FD, HD);
    gemm_down<<<NE * 16 * 16, 256, 0, stream>>>(hbuf, wgT, tok, rnk, cnt, yk);
    combine_kernel<<<NT, 256, 0, stream>>>(yk, wtok, y);
}

// Round 5
// 874.861 us; speedup vs baseline: 1.1653x; 1.0015x over previous
//
#include <hip/hip_runtime.h>
#include <math.h>

typedef unsigned short u16;
typedef unsigned int   u32;
typedef unsigned long long u64;
typedef __attribute__((ext_vector_type(8))) short short8;
typedef __attribute__((ext_vector_type(4))) float floatx4;
typedef __attribute__((ext_vector_type(4))) u16   u16x4;

#define NE   16      // experts
#define CAP  2048    // capacity per expert
#define HD   2048    // hidden
#define FD   1024    // intermediate
#define NT   4096    // tokens

// ---------- helpers ----------
__device__ __forceinline__ u16 f2bf(float f) {
    u32 u = __builtin_bit_cast(u32, f);
    u = (u + 0x7FFFu + ((u >> 16) & 1u)) >> 16;   // RNE
    return (u16)u;
}
__device__ __forceinline__ float bf2f(u16 v) {
    return __builtin_bit_cast(float, (u32)v << 16);
}

typedef const u32 __attribute__((address_space(1))) glb_u32;
typedef u32 __attribute__((address_space(3)))       lds_u32;

__device__ __forceinline__ void cp16(const void* g, void* l) {
    __builtin_amdgcn_global_load_lds((glb_u32*)g, (lds_u32*)l, 16, 0, 0);
}

__device__ __forceinline__ floatx4 mfma_bf16(short8 a, short8 b, floatx4 c) {
    return __builtin_amdgcn_mfma_f32_16x16x32_bf16(a, b, c, 0, 0, 0);
}

// XCD-contiguous swizzle: 4096 blocks, 8 XCDs. Default HW round-robin gives
// XCD = bid%8; remap so each XCD owns a contiguous 512-block chunk (= 2 experts).
__device__ __forceinline__ int xcd_swizzle(int bid0) {
    return ((bid0 & 7) << 9) | (bid0 >> 3);
}

// ---------- x -> bf16 ----------
__global__ void cvt_x_kernel(const float* __restrict__ x, u16* __restrict__ xb) {
    int i = blockIdx.x * 256 + threadIdx.x;
    float4 v = reinterpret_cast<const float4*>(x)[i];
    u16x4 o; o.x = f2bf(v.x); o.y = f2bf(v.y); o.z = f2bf(v.z); o.w = f2bf(v.w);
    reinterpret_cast<u16x4*>(xb)[i] = o;
}

// ---------- transpose + convert: in [R][Cc] fp32 -> out [Cc][R] bf16 (per expert) ----------
// Write phase vectorized: each thread packs 4 consecutive output elements (u16x4, 8B/lane).
__global__ void transpose_cvt(const float* __restrict__ in, u16* __restrict__ out,
                              int R, int Cc) {
    __shared__ u16 tile[64][65];
    int e = blockIdx.y;
    int tilesC = Cc >> 6;
    int tr = blockIdx.x / tilesC;
    int tc = blockIdx.x - tr * tilesC;
    const float* ip = in + (size_t)e * R * Cc + (size_t)(tr * 64) * Cc + tc * 64;
    u16* op = out + (size_t)e * R * Cc + (size_t)(tc * 64) * R + tr * 64;
    int c  = threadIdx.x & 63;
    int r0 = threadIdx.x >> 6;
    #pragma unroll
    for (int i = 0; i < 16; ++i) {
        int r = r0 + (i << 2);
        tile[r][c] = f2bf(ip[(size_t)r * Cc + c]);
    }
    __syncthreads();
    int rr0 = (threadIdx.x & 15) << 2;   // 0,4,...,60
    int cc0 = threadIdx.x >> 4;          // 0..15
    #pragma unroll
    for (int i = 0; i < 4; ++i) {
        int cc = cc0 + (i << 4);
        u16x4 v;
        v.x = tile[rr0 + 0][cc];
        v.y = tile[rr0 + 1][cc];
        v.z = tile[rr0 + 2][cc];
        v.w = tile[rr0 + 3][cc];
        *reinterpret_cast<u16x4*>(&op[(size_t)cc * R + rr0]) = v;
    }
}

// ---------- router phase 1: fp64-exact logits, top-4, softmax. NO atomics. ----------
// gw row loads vectorized as 4x float4 (same per-lane accumulation order as the
// scalar version -> bitwise-identical fp64 results).
__global__ void router_logits(const float* __restrict__ x, const float* __restrict__ gw,
                              float* __restrict__ logits, int* __restrict__ topi,
                              float* __restrict__ wtok) {
    int t = blockIdx.x;
    int l = threadIdx.x;      // 0..63
    const float* xr = x + (size_t)t * HD;
    double acc[NE];
    #pragma unroll
    for (int e = 0; e < NE; ++e) acc[e] = 0.0;
    for (int i = 0; i < HD / 64; ++i) {
        float xv = xr[l + (i << 6)];
        const float4* g4 = reinterpret_cast<const float4*>(gw + (size_t)(l + (i << 6)) * NE);
        float4 ga = g4[0], gb = g4[1], gc = g4[2], gd = g4[3];
        double xd = (double)xv;
        acc[0]  += xd * (double)ga.x;  acc[1]  += xd * (double)ga.y;
        acc[2]  += xd * (double)ga.z;  acc[3]  += xd * (double)ga.w;
        acc[4]  += xd * (double)gb.x;  acc[5]  += xd * (double)gb.y;
        acc[6]  += xd * (double)gb.z;  acc[7]  += xd * (double)gb.w;
        acc[8]  += xd * (double)gc.x;  acc[9]  += xd * (double)gc.y;
        acc[10] += xd * (double)gc.z;  acc[11] += xd * (double)gc.w;
        acc[12] += xd * (double)gd.x;  acc[13] += xd * (double)gd.y;
        acc[14] += xd * (double)gd.z;  acc[15] += xd * (double)gd.w;
    }
    #pragma unroll
    for (int e = 0; e < NE; ++e) {
        double v = acc[e];
        #pragma unroll
        for (int off = 1; off < 64; off <<= 1) v += __shfl_xor(v, off, 64);
        acc[e] = v;
    }
    if (l == 0) {
        #pragma unroll
        for (int e = 0; e < NE; ++e) logits[(size_t)t * NE + e] = (float)acc[e];
        int bi[4]; double bv[4];
        u32 used = 0;
        for (int k = 0; k < 4; ++k) {
            int best = 0; double bvv = -1e300;
            for (int e = 0; e < NE; ++e)
                if (!((used >> e) & 1u) && acc[e] > bvv) { bvv = acc[e]; best = e; }
            bi[k] = best; bv[k] = bvv; used |= 1u << best;
        }
        double s = 0.0, wv[4];
        for (int k = 0; k < 4; ++k) { wv[k] = exp(bv[k] - bv[0]); s += wv[k]; }
        for (int k = 0; k < 4; ++k) {
            topi[t * 4 + k] = bi[k];
            wtok[t * 4 + k] = (float)(wv[k] / s);
        }
    }
}

// ---------- router phase 2: atomic-free dispatch ----------
__global__ void dispatch_kernel(const int* __restrict__ topi, int* __restrict__ tok,
                                int* __restrict__ rnk, int* __restrict__ cnt) {
    int e = blockIdx.x;       // 0..15
    int l = threadIdx.x;      // 0..63
    u64 lanebit_m1 = (l == 0) ? 0ull : (~0ull >> (64 - l));
    int base = 0;
    #pragma unroll 4
    for (int s0 = 0; s0 < NT * 4; s0 += 64) {
        int s = s0 + l;
        int ex = topi[s];
        u64 m = __ballot(ex == e);
        if (ex == e) {
            int pos = base + __popcll(m & lanebit_m1);
            if (pos < CAP) {
                tok[e * CAP + pos] = s >> 2;
                rnk[e * CAP + pos] = s & 3;
            }
        }
        base += __popcll(m);
    }
    if (l == 0) cnt[e] = base;
}

// ---------- GEMM1: fused gate+up, 128x(64+64) tile, BK=64, double-buffered prefetch ----------
__global__ __launch_bounds__(256) void gemm_gateup(
        const u16* __restrict__ xb, const u16* __restrict__ wgT, const u16* __restrict__ wuT,
        const int* __restrict__ tok, const int* __restrict__ cnt, u16* __restrict__ hbuf) {
    int bid = xcd_swizzle(blockIdx.x);
    int e  = bid >> 8;
    int mt = (bid >> 4) & 15;
    int nt = bid & 15;
    int ne = cnt[e]; if (ne > CAP) ne = CAP;
    int row0 = mt << 7;
    if (row0 >= ne) return;

    __shared__ u16 As[2][128 * 64];
    __shared__ u16 Bg[2][64 * 64];
    __shared__ u16 Bu[2][64 * 64];
    __shared__ int toklds[128];

    int tid = threadIdx.x;
    if (tid < 128) {
        int r = row0 + tid;
        toklds[tid] = tok[e * CAP + (r < ne ? r : 0)];
    }
    __syncthreads();

    const u16* asrc[4];
    #pragma unroll
    for (int p = 0; p < 4; ++p) {
        int idx = tid + (p << 8);
        int r = idx >> 3;
        int c = (idx & 7) ^ (r & 7);            // XOR swizzle
        asrc[p] = xb + (size_t)toklds[r] * HD + (c << 3);
    }
    const u16* bgb = wgT + ((size_t)e * FD + (nt << 6)) * HD;
    const u16* bub = wuT + ((size_t)e * FD + (nt << 6)) * HD;
    const u16* bgsrc[2]; const u16* busrc[2];
    #pragma unroll
    for (int p = 0; p < 2; ++p) {
        int idx = tid + (p << 8);
        int r = idx >> 3;
        int c = (idx & 7) ^ (r & 7);            // XOR swizzle
        bgsrc[p] = bgb + (size_t)r * HD + (c << 3);
        busrc[p] = bub + (size_t)r * HD + (c << 3);
    }

    floatx4 accg[4][2], accu[4][2];
    #pragma unroll
    for (int i = 0; i < 4; ++i)
        #pragma unroll
        for (int j = 0; j < 2; ++j) {
            accg[i][j] = floatx4{0.f, 0.f, 0.f, 0.f};
            accu[i][j] = floatx4{0.f, 0.f, 0.f, 0.f};
        }

    int l = tid & 63, w = tid >> 6;
    int wm = (w >> 1) << 6;   // 0 / 64
    int wn = (w & 1) << 5;    // 0 / 32
    int lr = l & 15, q = l >> 4;
    int sw = lr & 7;          // swizzle key for fragment reads

    // prologue: stage tile 0 into buffer 0
    #pragma unroll
    for (int p = 0; p < 4; ++p) cp16(asrc[p], &As[0][(tid + (p << 8)) << 3]);
    #pragma unroll
    for (int p = 0; p < 2; ++p) {
        cp16(bgsrc[p], &Bg[0][(tid + (p << 8)) << 3]);
        cp16(busrc[p], &Bu[0][(tid + (p << 8)) << 3]);
    }
    __syncthreads();

    int cur = 0;
    for (int k0 = 64; k0 <= HD; k0 += 64) {
        if (k0 < HD) {
            int nx = cur ^ 1;
            #pragma unroll
            for (int p = 0; p < 4; ++p) cp16(asrc[p] + k0, &As[nx][(tid + (p << 8)) << 3]);
            #pragma unroll
            for (int p = 0; p < 2; ++p) {
                cp16(bgsrc[p] + k0, &Bg[nx][(tid + (p << 8)) << 3]);
                cp16(busrc[p] + k0, &Bu[nx][(tid + (p << 8)) << 3]);
            }
        }
        #pragma unroll
        for (int kk = 0; kk < 2; ++kk) {
            int ch = ((kk << 2) + q) ^ sw;      // swizzled chunk
            short8 af[4], bg[2], bu[2];
            #pragma unroll
            for (int mi = 0; mi < 4; ++mi)
                af[mi] = *(const short8*)&As[cur][((wm + mi * 16 + lr) << 6) + (ch << 3)];
            #pragma unroll
            for (int ni = 0; ni < 2; ++ni) {
                bg[ni] = *(const short8*)&Bg[cur][((wn + ni * 16 + lr) << 6) + (ch << 3)];
                bu[ni] = *(const short8*)&Bu[cur][((wn + ni * 16 + lr) << 6) + (ch << 3)];
            }
            #pragma unroll
            for (int mi = 0; mi < 4; ++mi)
                #pragma unroll
                for (int ni = 0; ni < 2; ++ni) {
                    accg[mi][ni] = mfma_bf16(af[mi], bg[ni], accg[mi][ni]);
                    accu[mi][ni] = mfma_bf16(af[mi], bu[ni], accu[mi][ni]);
                }
        }
        __syncthreads();
        cur ^= 1;
    }

    // epilogue: h = silu(g)*u, bf16 store
    #pragma unroll
    for (int mi = 0; mi < 4; ++mi) {
        #pragma unroll
        for (int r = 0; r < 4; ++r) {
            int rowl = wm + mi * 16 + q * 4 + r;
            int srow = row0 + rowl;
            if (srow < ne) {
                #pragma unroll
                for (int ni = 0; ni < 2; ++ni) {
                    float g = accg[mi][ni][r], u = accu[mi][ni][r];
                    float hv = g * u / (1.0f + __expf(-g));
                    hbuf[((size_t)e * CAP + srow) * FD + (nt << 6) + wn + ni * 16 + lr] = f2bf(hv);
                }
            }
        }
    }
}

// ---------- GEMM2: down-proj 128x128 tile, BK=64, atomic-free epilogue ----------
__global__ __launch_bounds__(256) void gemm_down(
        const u16* __restrict__ hbuf, const u16* __restrict__ wdT,
        const int* __restrict__ tok, const int* __restrict__ rnk,
        const int* __restrict__ cnt, u16* __restrict__ yk) {
    int bid = xcd_swizzle(blockIdx.x);
    int e  = bid >> 8;
    int mt = (bid >> 4) & 15;
    int nt = bid & 15;
    int ne = cnt[e]; if (ne > CAP) ne = CAP;
    int row0 = mt << 7;
    if (row0 >= ne) return;

    __shared__ u16 As[2][128 * 64];
    __shared__ u16 Bs[2][128 * 64];
    __shared__ int toklds[128];
    __shared__ int rklds[128];

    int tid = threadIdx.x;
    if (tid < 128) {
        int r = row0 + tid;
        int ok = (r < ne);
        toklds[tid] = ok ? tok[e * CAP + r] : 0;
        rklds[tid]  = ok ? rnk[e * CAP + r] : 0;
    }

    const u16* ab = hbuf + ((size_t)e * CAP + row0) * FD;
    const u16* bb = wdT + ((size_t)e * HD + (nt << 7)) * FD;
    const u16* asrc[4]; const u16* bsrc[4];
    #pragma unroll
    for (int p = 0; p < 4; ++p) {
        int idx = tid + (p << 8);
        int r = idx >> 3;
        int c = (idx & 7) ^ (r & 7);            // XOR swizzle
        asrc[p] = ab + (size_t)r * FD + (c << 3);
        bsrc[p] = bb + (size_t)r * FD + (c << 3);
    }

    floatx4 acc[4][4];
    #pragma unroll
    for (int i = 0; i < 4; ++i)
        #pragma unroll
        for (int j = 0; j < 4; ++j) acc[i][j] = floatx4{0.f, 0.f, 0.f, 0.f};

    int l = tid & 63, w = tid >> 6;
    int wm = (w >> 1) << 6;
    int wn = (w & 1) << 6;
    int lr = l & 15, q = l >> 4;
    int sw = lr & 7;

    // prologue: stage tile 0 into buffer 0
    #pragma unroll
    for (int p = 0; p < 4; ++p) {
        cp16(asrc[p], &As[0][(tid + (p << 8)) << 3]);
        cp16(bsrc[p], &Bs[0][(tid + (p << 8)) << 3]);
    }
    __syncthreads();

    int cur = 0;
    for (int k0 = 64; k0 <= FD; k0 += 64) {
        if (k0 < FD) {
            int nx = cur ^ 1;
            #pragma unroll
            for (int p = 0; p < 4; ++p) {
                cp16(asrc[p] + k0, &As[nx][(tid + (p << 8)) << 3]);
                cp16(bsrc[p] + k0, &Bs[nx][(tid + (p << 8)) << 3]);
            }
        }
        #pragma unroll
        for (int kk = 0; kk < 2; ++kk) {
            int ch = ((kk << 2) + q) ^ sw;
            short8 af[4], bf[4];
            #pragma unroll
            for (int mi = 0; mi < 4; ++mi)
                af[mi] = *(const short8*)&As[cur][((wm + mi * 16 + lr) << 6) + (ch << 3)];
            #pragma unroll
            for (int ni = 0; ni < 4; ++ni)
                bf[ni] = *(const short8*)&Bs[cur][((wn + ni * 16 + lr) << 6) + (ch << 3)];
            #pragma unroll
            for (int mi = 0; mi < 4; ++mi)
                #pragma unroll
                for (int ni = 0; ni < 4; ++ni)
                    acc[mi][ni] = mfma_bf16(af[mi], bf[ni], acc[mi][ni]);
        }
        __syncthreads();
        cur ^= 1;
    }

    #pragma unroll
    for (int mi = 0; mi < 4; ++mi) {
        #pragma unroll
        for (int r = 0; r < 4; ++r) {
            int rowl = wm + mi * 16 + q * 4 + r;
            if (row0 + rowl < ne) {
                int tv = toklds[rowl];
                int rk = rklds[rowl];
                u16* yr = yk + ((size_t)rk * NT + tv) * HD + (nt << 7) + wn + lr;
                #pragma unroll
                for (int ni = 0; ni < 4; ++ni)
                    yr[ni * 16] = f2bf(acc[mi][ni][r]);
            }
        }
    }
}

// ---------- combine: y[t] = sum_k wtok[t][k] * yk[k][t]  (fully overwrites y) ----------
__global__ __launch_bounds__(256) void combine_kernel(
        const u16* __restrict__ yk, const float* __restrict__ wtok,
        float* __restrict__ y) {
    int t = blockIdx.x;
    int h0 = threadIdx.x << 3;     // 8 elements per thread
    float wk[4];
    #pragma unroll
    for (int k = 0; k < 4; ++k) wk[k] = wtok[t * 4 + k];
    float acc[8];
    #pragma unroll
    for (int j = 0; j < 8; ++j) acc[j] = 0.f;
    #pragma unroll
    for (int k = 0; k < 4; ++k) {
        short8 v = *reinterpret_cast<const short8*>(&yk[((size_t)k * NT + t) * HD + h0]);
        #pragma unroll
        for (int j = 0; j < 8; ++j) acc[j] += wk[k] * bf2f((u16)v[j]);
    }
    float4 o0{acc[0], acc[1], acc[2], acc[3]};
    float4 o1{acc[4], acc[5], acc[6], acc[7]};
    float4* yo = reinterpret_cast<float4*>(y + (size_t)t * HD + h0);
    yo[0] = o0; yo[1] = o1;
}

// ---------- launch ----------
extern "C" void kernel_launch(void* const* d_in, const int* in_sizes, int n_in,
                              void* d_out, int out_size, void* d_ws, size_t ws_size,
                              hipStream_t stream) {
    const float* x      = (const float*)d_in[0];
    const float* gw     = (const float*)d_in[1];
    const float* w_gate = (const float*)d_in[2];
    const float* w_up   = (const float*)d_in[3];
    const float* w_down = (const float*)d_in[4];

    float* y      = (float*)d_out;
    float* logits = y + (size_t)NT * HD;

    char* ws = (char*)d_ws;
    const size_t SZ_WT = (size_t)NE * FD * HD * 2;            // 64 MB
    u16* wgT  = (u16*)(ws);                                   // later reused as wdT
    u16* wuT  = (u16*)(ws + SZ_WT);
    u16* xb   = (u16*)(ws + 2 * SZ_WT);
    u16* hbuf = (u16*)(ws + 2 * SZ_WT + (size_t)NT * HD * 2);
    // yk[4][NT][HD] bf16 (67 MB) overlays wuT (64 MB) + head of xb (3 MB);
    // both are dead by the time gemm_down runs (stream-ordered after gemm_gateup).
    u16* yk   = (u16*)(ws + SZ_WT);
    char* tail = ws + 2 * SZ_WT + (size_t)NT * HD * 2 + (size_t)NE * CAP * FD * 2;
    int*   tok  = (int*)(tail);
    int*   rnk  = (int*)(tail + (size_t)NE * CAP * 4);
    float* wtok = (float*)(tail + 2 * (size_t)NE * CAP * 4);
    int*   topi = (int*)(tail + 2 * (size_t)NE * CAP * 4 + (size_t)NT * 4 * 4);
    int*   cnt  = (int*)(tail + 2 * (size_t)NE * CAP * 4 + 2 * (size_t)NT * 4 * 4);

    cvt_x_kernel<<<(NT * HD / 4) / 256, 256, 0, stream>>>(x, xb);
    transpose_cvt<<<dim3((HD / 64) * (FD / 64), NE), 256, 0, stream>>>(w_gate, wgT, HD, FD);
    transpose_cvt<<<dim3((HD / 64) * (FD / 64), NE), 256, 0, stream>>>(w_up,   wuT, HD, FD);
    router_logits<<<NT, 64, 0, stream>>>(x, gw, logits, topi, wtok);
    dispatch_kernel<<<NE, 64, 0, stream>>>(topi, tok, rnk, cnt);
    gemm_gateup<<<NE * 16 * 16, 256, 0, stream>>>(xb, wgT, wuT, tok, cnt, hbuf);
    // reuse wgT region for transposed w_down (stream-ordered after gemm_gateup)
    transpose_cvt<<<dim3((FD / 64) * (HD / 64), NE), 256, 0, stream>>>(w_down, wgT, FD, HD);
    gemm_down<<<NE * 16 * 16, 256, 0, stream>>>(hbuf, wgT, tok, rnk, cnt, yk);
    combine_kernel<<<NT, 256, 0, stream>>>(yk, wtok, y);
}